// Round 3
// baseline (177.125 us; speedup 1.0000x reference)
//
#include <hip/hip_runtime.h>
#include <math.h>

// Problem constants
#define Gc 36
#define Ac 5
#define Bc 32
#define Tc 8
#define NCELLS (Bc*Gc*Gc*Ac)     // 207360
#define NF4 (NCELLS*5/4)         // 259200 float4 chunks of bbox_pred
#define NT 256
#define NB 256

// ws layout (first 64 B zeroed via hipMemsetAsync before the kernel):
//   ws_i[0] completion counter
//   ws_f[1] conf^2 total        ws_f[2] sum_nme (pre-/nobj)
//   ws_f[3] sum_sl1             ws_f[4] sum_cobj
//   ws_f[5] sum_csq(obj cells)  ws_i[6] winner count

__device__ __forceinline__ void target_meta(const float* __restrict__ bbox_tgt,
                                            int tgt, bool& valid, int& gi, int& gj,
                                            float& fx, float& fy, float& w, float& h,
                                            int& best_a) {
    const float* tg = bbox_tgt + (size_t)tgt * 4;
    float x = tg[0], y = tg[1];
    w = tg[2]; h = tg[3];
    valid = ((x + y + w + h) != 0.0f);
    float gx = x * (float)Gc, gy = y * (float)Gc;
    gi = (int)floorf(gx); gj = (int)floorf(gy);
    fx = gx - floorf(gx); fy = gy - floorf(gy);

    // anchor IoU argmax (first-max tie-break via strict >)
    float x1a = fx - w * 0.5f, x2a = fx + w * 0.5f;
    float y1a = fy - h * 0.5f, y2a = fy + h * 0.5f;
    float a1 = (x2a - x1a + 1.0f) * (y2a - y1a + 1.0f);
    const float adim[Ac] = {0.24f, 0.12f, 0.08f, 0.28f, 0.15f};
    best_a = 0;
    float best_iou = -1e30f;
    for (int a = 0; a < Ac; ++a) {
        float x1b = 0.5f - adim[a] * 0.5f, x2b = 0.5f + adim[a] * 0.5f;
        float iw = fminf(x2a, x2b) - fmaxf(x1a, x1b) + 1.0f;
        float ih = fminf(y2a, x2b) - fmaxf(y1a, x1b) + 1.0f;  // square anchors
        float inter = iw * ih;
        float a2 = (x2b - x1b + 1.0f) * (x2b - x1b + 1.0f);
        float iou = inter / (a1 + a2 - inter + 1e-16f);
        if (iou > best_iou) { best_iou = iou; best_a = a; }
    }
}

__global__ __launch_bounds__(NT) void fused(
        const float* __restrict__ bbox_pred,
        const float* __restrict__ lm_pred,
        const float* __restrict__ bbox_tgt,
        const float* __restrict__ lm_tgt,
        float* __restrict__ ws_f, int* __restrict__ ws_i,
        float* __restrict__ out) {
    const int tid = threadIdx.x;
    const int bid = blockIdx.x;              // == target index 0..255
    __shared__ float red[NT];
    __shared__ int s_lin8[8];

    // ---- coalesced conf^2 partial over this block's slice ----
    const float4* p4 = (const float4*)bbox_pred;
    float acc = 0.0f;
    for (int j = bid * NT + tid; j < NF4; j += NB * NT) {
        float4 f = p4[j];
        int r = (4 * j) % 5;  // position of f.x within its 5-float cell
        float v = (r == 4) ? f.x : (r == 3) ? f.y : (r == 2) ? f.z
                : (r == 1) ? f.w : 0.0f;
        acc += v * v;
    }
    red[tid] = acc;
    __syncthreads();
    for (int s = NT / 2; s > 0; s >>= 1) {
        if (tid < s) red[tid] += red[tid + s];
        __syncthreads();
    }
    // red[0] = block conf^2 partial (preserved below; red not reused)

    // ---- per-target metadata: lanes 0..7 compute lin for batch b ----
    const int tgt = bid;
    const int b = tgt >> 3, t = tgt & 7;
    if (tid < 8) {
        bool v; int gi, gj, ba; float fx, fy, w, h;
        target_meta(bbox_tgt, (b << 3) + tid, v, gi, gj, fx, fy, w, h, ba);
        s_lin8[tid] = v ? (((b * Gc + gj) * Gc + gi) * Ac + ba) : NCELLS;
    }
    __syncthreads();

    if (tid < 64) {  // wave 0 handles target `tgt`
        int lin = s_lin8[t];
        bool valid = (lin != NCELLS);
        bool winner = valid;
        if (valid)
            for (int t2 = t + 1; t2 < Tc; ++t2)
                if (s_lin8[t2] == lin) { winner = false; break; }

        // landmark L2 distance^2, wave-parallel (34 float4 pairs)
        float a2 = 0.0f;
        if (winner && tid < 34) {
            const float4* lp = (const float4*)(lm_pred + (size_t)lin * 136);
            const float4* lt = (const float4*)(lm_tgt + (size_t)tgt * 136);
            float4 a = lp[tid], c = lt[tid];
            float dx = a.x - c.x, dy = a.y - c.y, dz = a.z - c.z, dw = a.w - c.w;
            a2 = dx * dx + dy * dy + dz * dz + dw * dw;
        }
        for (int off = 32; off > 0; off >>= 1)
            a2 += __shfl_down(a2, off, 64);

        if (tid == 0) {
            bool v; int gi, gj, ba; float fx, fy, w, h;
            target_meta(bbox_tgt, tgt, v, gi, gj, fx, fy, w, h, ba);
            float l0 = log1pf(fx), l1 = log1pf(fy), l2 = log1pf(w), l3 = log1pf(h);

            float c_nme = 0.0f, c_sl1 = 0.0f, c_cobj = 0.0f, c_csq = 0.0f;
            if (winner) {
                const float* bp = bbox_pred + (size_t)lin * 5;
                float conf = bp[4];
                c_cobj = (conf - 1.0f) * (conf - 1.0f);
                c_csq = conf * conf;
                float lb[4] = {l0, l1, l2, l3};
                for (int k = 0; k < 4; ++k) {
                    float d = bp[k] - lb[k];
                    float ad = fabsf(d);
                    c_sl1 += (ad < 1.0f) ? 0.5f * d * d : (ad - 0.5f);
                }
                c_nme = sqrtf(a2) / (sqrtf(l2 * l3) * 288.0f * 68.0f);
            }

            // best_pred for this target (scattered ~2 cache lines)
            const float* cp = bbox_pred + (size_t)((b * Gc + gj) * Gc + gi) * Ac * 5;
            float x1g = l0 - l2 * 0.5f, x2g = l0 + l2 * 0.5f;
            float y1g = l1 - l3 * 0.5f, y2g = l1 + l3 * 0.5f;
            float ag = (x2g - x1g + 1.0f) * (y2g - y1g + 1.0f);
            int bp_idx = 0;
            float bp_iou = -1e30f;
            for (int a = 0; a < Ac; ++a) {
                float cx = cp[a * 5 + 0], cy = cp[a * 5 + 1];
                float pw = cp[a * 5 + 2], ph = cp[a * 5 + 3];
                float x1p = cx - pw * 0.5f, x2p = cx + pw * 0.5f;
                float y1p = cy - ph * 0.5f, y2p = cy + ph * 0.5f;
                float iw = fminf(x2g, x2p) - fmaxf(x1g, x1p) + 1.0f;
                float ih = fminf(y2g, y2p) - fmaxf(y1g, y1p) + 1.0f;
                float inter = iw * ih;
                float ap = (x2p - x1p + 1.0f) * (y2p - y1p + 1.0f);
                float iou = inter / (ag + ap - inter + 1e-16f);
                if (iou > bp_iou) { bp_iou = iou; bp_idx = a; }
            }
            float* op = out + 3 + (size_t)tgt * 5;
            if (v) {
                float bx = cp[bp_idx * 5 + 0], by = cp[bp_idx * 5 + 1];
                float bw = cp[bp_idx * 5 + 2], bh = cp[bp_idx * 5 + 3];
                op[0] = bx - bw * 0.5f; op[1] = bx + bw * 0.5f;
                op[2] = by - bh * 0.5f; op[3] = by + bh * 0.5f;
                op[4] = cp[bp_idx * 5 + 4];
            } else {
                op[0] = 0.0f; op[1] = 0.0f; op[2] = 0.0f; op[3] = 0.0f; op[4] = 0.0f;
            }

            // ---- global accumulation + last-block finalize ----
            atomicAdd(&ws_f[1], red[0]);
            if (winner) {
                atomicAdd(&ws_f[2], c_nme);
                atomicAdd(&ws_f[3], c_sl1);
                atomicAdd(&ws_f[4], c_cobj);
                atomicAdd(&ws_f[5], c_csq);
                atomicAdd(&ws_i[6], 1);
            }
            __threadfence();
            int done = atomicAdd(&ws_i[0], 1);
            if (done == NB - 1) {   // last block to finish combines
                __threadfence();
                float total = atomicAdd(&ws_f[1], 0.0f);
                float snme  = atomicAdd(&ws_f[2], 0.0f);
                float ssl1  = atomicAdd(&ws_f[3], 0.0f);
                float scobj = atomicAdd(&ws_f[4], 0.0f);
                float scsq  = atomicAdd(&ws_f[5], 0.0f);
                int   cnt   = atomicAdd(&ws_i[6], 0);
                float nobj = fmaxf((float)cnt, 1.0f);
                float n_noobj = fmaxf((float)(NCELLS - cnt), 1.0f);
                out[0] = snme / nobj;
                out[1] = 5.0f * ssl1 / (nobj * 4.0f);
                out[2] = 0.5f * (total - scsq) / n_noobj + scobj / nobj;
            }
        }
    }
}

extern "C" void kernel_launch(void* const* d_in, const int* in_sizes, int n_in,
                              void* d_out, int out_size, void* d_ws, size_t ws_size,
                              hipStream_t stream) {
    const float* bbox_pred = (const float*)d_in[0];
    const float* lm_pred   = (const float*)d_in[1];
    const float* bbox_tgt  = (const float*)d_in[2];
    const float* lm_tgt    = (const float*)d_in[3];
    float* out = (float*)d_out;
    float* ws_f = (float*)d_ws;
    int*   ws_i = (int*)d_ws;

    hipMemsetAsync(d_ws, 0, 64, stream);  // zero counter + accumulators
    fused<<<NB, NT, 0, stream>>>(bbox_pred, lm_pred, bbox_tgt, lm_tgt,
                                 ws_f, ws_i, out);
}

// Round 4
// 160.328 us; speedup vs baseline: 1.1048x; 1.1048x over previous
//
#include <hip/hip_runtime.h>
#include <math.h>

// Problem constants (from reference)
#define Gc 36
#define Ac 5
#define Bc 32
#define Tc 8
#define NCELLS (Bc*Gc*Gc*Ac)     // 207360
#define NFLOATS (NCELLS*5)       // 1036800
#define NF4 (NFLOATS/4)          // 259200
#define NT 256
#define CONF_BLOCKS 128

// ws layout (floats / ints):
//   ws_f[0..127]          conf^2 partials (CONF_BLOCKS)
//   ws_i[256..511]        lin per target
//   ws_i[512..767]        winner flag per target
//   ws_f[1024..1279]      landmark dist per target (0 for non-winner)

__device__ __forceinline__ void target_meta(const float* __restrict__ bbox_tgt,
                                            int tid, bool& valid, int& gi, int& gj,
                                            float& fx, float& fy, float& w, float& h,
                                            int& best_a) {
    const int b = tid >> 3, t = tid & 7;
    const float* tg = bbox_tgt + (size_t)(b * Tc + t) * 4;
    float x = tg[0], y = tg[1];
    w = tg[2]; h = tg[3];
    valid = ((x + y + w + h) != 0.0f);
    float gx = x * (float)Gc, gy = y * (float)Gc;
    gi = (int)floorf(gx); gj = (int)floorf(gy);
    fx = gx - floorf(gx); fy = gy - floorf(gy);

    // anchor IoU argmax (first-max tie-break via strict >)
    float x1a = fx - w * 0.5f, x2a = fx + w * 0.5f;
    float y1a = fy - h * 0.5f, y2a = fy + h * 0.5f;
    float a1 = (x2a - x1a + 1.0f) * (y2a - y1a + 1.0f);
    const float adim[Ac] = {0.24f, 0.12f, 0.08f, 0.28f, 0.15f};
    best_a = 0;
    float best_iou = -1e30f;
    for (int a = 0; a < Ac; ++a) {
        float x1b = 0.5f - adim[a] * 0.5f, x2b = 0.5f + adim[a] * 0.5f;
        float iw = fminf(x2a, x2b) - fmaxf(x1a, x1b) + 1.0f;
        float ih = fminf(y2a, x2b) - fmaxf(y1a, x1b) + 1.0f;  // square anchors
        float inter = iw * ih;
        float a2 = (x2b - x1b + 1.0f) * (x2b - x1b + 1.0f);
        float iou = inter / (a1 + a2 - inter + 1e-16f);
        if (iou > best_iou) { best_iou = iou; best_a = a; }
    }
}

// ---------------------------------------------------------------------------
// K1: blocks 0..CONF_BLOCKS-1 -> conf^2 partials (float4).  block CONF_BLOCKS
//     -> per-target meta (lin, winner) into ws.
// ---------------------------------------------------------------------------
__global__ __launch_bounds__(NT) void k1_conf_meta(
        const float* __restrict__ bbox_pred,
        const float* __restrict__ bbox_tgt,
        float* __restrict__ ws_f, int* __restrict__ ws_i) {
    if (blockIdx.x < CONF_BLOCKS) {
        __shared__ float red[NT];
        const float4* p4 = (const float4*)bbox_pred;
        float acc = 0.0f;
        for (int j = blockIdx.x * NT + threadIdx.x; j < NF4;
             j += CONF_BLOCKS * NT) {
            float4 f = p4[j];
            int r = (4 * j) % 5;   // position of f.x within its 5-group
            float v = (r == 4) ? f.x : (r == 3) ? f.y : (r == 2) ? f.z
                    : (r == 1) ? f.w : 0.0f;
            acc += v * v;
        }
        red[threadIdx.x] = acc;
        __syncthreads();
        for (int s = NT / 2; s > 0; s >>= 1) {
            if (threadIdx.x < s) red[threadIdx.x] += red[threadIdx.x + s];
            __syncthreads();
        }
        if (threadIdx.x == 0) ws_f[blockIdx.x] = red[0];
    } else {
        // meta block
        __shared__ int s_lin[NT];
        const int tid = threadIdx.x;
        const int b = tid >> 3, t = tid & 7;
        bool valid; int gi, gj, best_a; float fx, fy, w, h;
        target_meta(bbox_tgt, tid, valid, gi, gj, fx, fy, w, h, best_a);
        int lin = valid ? (((b * Gc + gj) * Gc + gi) * Ac + best_a) : NCELLS;
        s_lin[tid] = lin;
        __syncthreads();
        bool winner = valid;
        if (valid) {
            for (int t2 = t + 1; t2 < Tc; ++t2)
                if (s_lin[(b << 3) + t2] == lin) { winner = false; break; }
        }
        ws_i[256 + tid] = lin;
        ws_i[512 + tid] = winner ? 1 : 0;
    }
}

// ---------------------------------------------------------------------------
// K2: one wave per target -> landmark L2 distance (0 if not winner)
// ---------------------------------------------------------------------------
__global__ __launch_bounds__(64) void k2_lmdist(
        const float* __restrict__ lm_pred,
        const float* __restrict__ lm_tgt,
        const int* __restrict__ ws_i,
        float* __restrict__ ws_f) {
    const int tgt = blockIdx.x;          // 0..255
    const int lane = threadIdx.x;        // 0..63
    int winner = ws_i[512 + tgt];
    int lin = ws_i[256 + tgt];
    float acc = 0.0f;
    if (winner && lane < 34) {
        const float4* lp = (const float4*)(lm_pred + (size_t)lin * 136);
        const float4* lt = (const float4*)(lm_tgt + (size_t)tgt * 136);
        float4 a = lp[lane], b = lt[lane];
        float dx = a.x - b.x, dy = a.y - b.y, dz = a.z - b.z, dw = a.w - b.w;
        acc = dx * dx + dy * dy + dz * dz + dw * dw;
    }
    // wave reduction over 64 lanes
    for (int off = 32; off > 0; off >>= 1)
        acc += __shfl_down(acc, off, 64);
    if (lane == 0) ws_f[1024 + tgt] = winner ? sqrtf(acc) : 0.0f;
}

// ---------------------------------------------------------------------------
// K3: final combine (1 block, 256 threads = one thread per target)
// ---------------------------------------------------------------------------
__device__ __forceinline__ float block_sum(float v, float* red, int tid) {
    red[tid] = v;
    __syncthreads();
    for (int s = NT / 2; s > 0; s >>= 1) {
        if (tid < s) red[tid] += red[tid + s];
        __syncthreads();
    }
    float r = red[0];
    __syncthreads();
    return r;
}

__global__ __launch_bounds__(NT) void k3_final(
        const float* __restrict__ bbox_pred,
        const float* __restrict__ bbox_tgt,
        const float* __restrict__ ws_f,
        const int* __restrict__ ws_i,
        float* __restrict__ out) {
    const int tid = threadIdx.x;
    const int b = tid >> 3, t = tid & 7;
    __shared__ float s_red[NT];
    __shared__ int s_cnt[NT];

    bool valid; int gi, gj, best_a; float fx, fy, w, h;
    target_meta(bbox_tgt, tid, valid, gi, gj, fx, fy, w, h, best_a);
    int lin = ws_i[256 + tid];
    int winner = ws_i[512 + tid];
    float dist = ws_f[1024 + tid];

    float l0 = log1pf(fx), l1 = log1pf(fy), l2 = log1pf(w), l3 = log1pf(h);

    float c_nme = 0.0f, c_sl1 = 0.0f, c_cobj = 0.0f, c_csq = 0.0f;
    if (winner) {
        const float* bp = bbox_pred + (size_t)lin * 5;
        float conf = bp[4];
        c_cobj = (conf - 1.0f) * (conf - 1.0f);
        c_csq = conf * conf;
        float lb[4] = {l0, l1, l2, l3};
        for (int k = 0; k < 4; ++k) {
            float d = bp[k] - lb[k];
            float ad = fabsf(d);
            c_sl1 += (ad < 1.0f) ? 0.5f * d * d : (ad - 0.5f);
        }
        c_nme = dist / (sqrtf(l2 * l3) * 288.0f * 68.0f);
    }

    s_cnt[tid] = winner;
    __syncthreads();
    for (int s = NT / 2; s > 0; s >>= 1) {
        if (tid < s) s_cnt[tid] += s_cnt[tid + s];
        __syncthreads();
    }
    int cnt = s_cnt[0];
    __syncthreads();
    float nobj = fmaxf((float)cnt, 1.0f);
    float n_noobj = fmaxf((float)(NCELLS - cnt), 1.0f);

    float sum_nme  = block_sum(c_nme, s_red, tid);
    float sum_sl1  = block_sum(c_sl1, s_red, tid);
    float sum_cobj = block_sum(c_cobj, s_red, tid);
    float sum_csq  = block_sum(c_csq, s_red, tid);
    float s_total  = block_sum(tid < CONF_BLOCKS ? ws_f[tid] : 0.0f, s_red, tid);

    if (tid == 0) {
        out[0] = sum_nme / nobj;
        out[1] = 5.0f * sum_sl1 / (nobj * 4.0f);
        out[2] = 0.5f * (s_total - sum_csq) / n_noobj + sum_cobj / nobj;
    }

    // best_pred per target
    const float* cp = bbox_pred + (size_t)((b * Gc + gj) * Gc + gi) * Ac * 5;
    float x1g = l0 - l2 * 0.5f, x2g = l0 + l2 * 0.5f;
    float y1g = l1 - l3 * 0.5f, y2g = l1 + l3 * 0.5f;
    float ag = (x2g - x1g + 1.0f) * (y2g - y1g + 1.0f);
    int bp_idx = 0;
    float bp_iou = -1e30f;
    for (int a = 0; a < Ac; ++a) {
        float cx = cp[a * 5 + 0], cy = cp[a * 5 + 1];
        float pw = cp[a * 5 + 2], ph = cp[a * 5 + 3];
        float x1p = cx - pw * 0.5f, x2p = cx + pw * 0.5f;
        float y1p = cy - ph * 0.5f, y2p = cy + ph * 0.5f;
        float iw = fminf(x2g, x2p) - fmaxf(x1g, x1p) + 1.0f;
        float ih = fminf(y2g, y2p) - fmaxf(y1g, y1p) + 1.0f;
        float inter = iw * ih;
        float ap = (x2p - x1p + 1.0f) * (y2p - y1p + 1.0f);
        float iou = inter / (ag + ap - inter + 1e-16f);
        if (iou > bp_iou) { bp_iou = iou; bp_idx = a; }
    }
    float bx = cp[bp_idx * 5 + 0], by = cp[bp_idx * 5 + 1];
    float bw = cp[bp_idx * 5 + 2], bh = cp[bp_idx * 5 + 3];
    float bconf = cp[bp_idx * 5 + 4];
    float* op = out + 3 + (size_t)tid * 5;
    if (valid) {
        op[0] = bx - bw * 0.5f; op[1] = bx + bw * 0.5f;
        op[2] = by - bh * 0.5f; op[3] = by + bh * 0.5f; op[4] = bconf;
    } else {
        op[0] = 0.0f; op[1] = 0.0f; op[2] = 0.0f; op[3] = 0.0f; op[4] = 0.0f;
    }
}

extern "C" void kernel_launch(void* const* d_in, const int* in_sizes, int n_in,
                              void* d_out, int out_size, void* d_ws, size_t ws_size,
                              hipStream_t stream) {
    const float* bbox_pred = (const float*)d_in[0];
    const float* lm_pred   = (const float*)d_in[1];
    const float* bbox_tgt  = (const float*)d_in[2];
    const float* lm_tgt    = (const float*)d_in[3];
    float* out = (float*)d_out;
    float* ws_f = (float*)d_ws;
    int* ws_i = (int*)d_ws;

    k1_conf_meta<<<CONF_BLOCKS + 1, NT, 0, stream>>>(bbox_pred, bbox_tgt, ws_f, ws_i);
    k2_lmdist<<<256, 64, 0, stream>>>(lm_pred, lm_tgt, ws_i, ws_f);
    k3_final<<<1, NT, 0, stream>>>(bbox_pred, bbox_tgt, ws_f, ws_i, out);
}

// Round 5
// 157.484 us; speedup vs baseline: 1.1247x; 1.0181x over previous
//
#include <hip/hip_runtime.h>
#include <math.h>

// Problem constants (from reference)
#define Gc 36
#define Ac 5
#define Bc 32
#define Tc 8
#define NCELLS (Bc*Gc*Gc*Ac)     // 207360
#define NFLOATS (NCELLS*5)       // 1036800
#define NF4 (NFLOATS/4)          // 259200
#define NT 256
#define CONF_BLOCKS 128

// ws layout (floats / ints):
//   ws_f[0..127]          conf^2 partials (CONF_BLOCKS)
//   ws_i[256..511]        lin per target
//   ws_i[512..767]        winner flag per target
//   ws_f[1024..1279]      landmark dist per target (0 for non-winner)

__device__ __forceinline__ void target_meta(const float* __restrict__ bbox_tgt,
                                            int tgt, bool& valid, int& gi, int& gj,
                                            float& fx, float& fy, float& w, float& h,
                                            int& best_a) {
    const float* tg = bbox_tgt + (size_t)tgt * 4;
    float x = tg[0], y = tg[1];
    w = tg[2]; h = tg[3];
    valid = ((x + y + w + h) != 0.0f);
    float gx = x * (float)Gc, gy = y * (float)Gc;
    gi = (int)floorf(gx); gj = (int)floorf(gy);
    fx = gx - floorf(gx); fy = gy - floorf(gy);

    // anchor IoU argmax (first-max tie-break via strict >)
    float x1a = fx - w * 0.5f, x2a = fx + w * 0.5f;
    float y1a = fy - h * 0.5f, y2a = fy + h * 0.5f;
    float a1 = (x2a - x1a + 1.0f) * (y2a - y1a + 1.0f);
    const float adim[Ac] = {0.24f, 0.12f, 0.08f, 0.28f, 0.15f};
    best_a = 0;
    float best_iou = -1e30f;
    for (int a = 0; a < Ac; ++a) {
        float x1b = 0.5f - adim[a] * 0.5f, x2b = 0.5f + adim[a] * 0.5f;
        float iw = fminf(x2a, x2b) - fmaxf(x1a, x1b) + 1.0f;
        float ih = fminf(y2a, x2b) - fmaxf(y1a, x1b) + 1.0f;  // square anchors
        float inter = iw * ih;
        float a2 = (x2b - x1b + 1.0f) * (x2b - x1b + 1.0f);
        float iou = inter / (a1 + a2 - inter + 1e-16f);
        if (iou > best_iou) { best_iou = iou; best_a = a; }
    }
}

// ---------------------------------------------------------------------------
// K12: blocks 0..127 -> conf^2 partials (float4, coalesced).
//      blocks 128..383 -> per-target meta (recomputed locally) + landmark dist.
//      No inter-block dependency -> both halves run concurrently.
// ---------------------------------------------------------------------------
__global__ __launch_bounds__(NT) void k12_conf_lm(
        const float* __restrict__ bbox_pred,
        const float* __restrict__ lm_pred,
        const float* __restrict__ bbox_tgt,
        const float* __restrict__ lm_tgt,
        float* __restrict__ ws_f, int* __restrict__ ws_i) {
    if (blockIdx.x < CONF_BLOCKS) {
        __shared__ float red[NT];
        const float4* p4 = (const float4*)bbox_pred;
        float acc = 0.0f;
        for (int j = blockIdx.x * NT + threadIdx.x; j < NF4;
             j += CONF_BLOCKS * NT) {
            float4 f = p4[j];
            int r = (4 * j) % 5;   // position of f.x within its 5-group
            float v = (r == 4) ? f.x : (r == 3) ? f.y : (r == 2) ? f.z
                    : (r == 1) ? f.w : 0.0f;
            acc += v * v;
        }
        red[threadIdx.x] = acc;
        __syncthreads();
        for (int s = NT / 2; s > 0; s >>= 1) {
            if (threadIdx.x < s) red[threadIdx.x] += red[threadIdx.x + s];
            __syncthreads();
        }
        if (threadIdx.x == 0) ws_f[blockIdx.x] = red[0];
    } else {
        const int tgt = blockIdx.x - CONF_BLOCKS;   // 0..255
        const int b = tgt >> 3, t = tgt & 7;
        const int tid = threadIdx.x;
        __shared__ int s_lin8[8];

        if (tid < 8) {   // lanes 0..7: lin for this batch's 8 targets
            bool v; int gi, gj, ba; float fx, fy, w, h;
            target_meta(bbox_tgt, (b << 3) + tid, v, gi, gj, fx, fy, w, h, ba);
            s_lin8[tid] = v ? (((b * Gc + gj) * Gc + gi) * Ac + ba) : NCELLS;
        }
        __syncthreads();

        if (tid < 64) {
            int lin = s_lin8[t];
            bool valid = (lin != NCELLS);
            bool winner = valid;
            if (valid)
                for (int t2 = t + 1; t2 < Tc; ++t2)
                    if (s_lin8[t2] == lin) { winner = false; break; }

            float acc = 0.0f;
            if (winner && tid < 34) {
                const float4* lp = (const float4*)(lm_pred + (size_t)lin * 136);
                const float4* lt = (const float4*)(lm_tgt + (size_t)tgt * 136);
                float4 a = lp[tid], c = lt[tid];
                float dx = a.x - c.x, dy = a.y - c.y;
                float dz = a.z - c.z, dw = a.w - c.w;
                acc = dx * dx + dy * dy + dz * dz + dw * dw;
            }
            for (int off = 32; off > 0; off >>= 1)
                acc += __shfl_down(acc, off, 64);

            if (tid == 0) {
                ws_i[256 + tgt] = lin;
                ws_i[512 + tgt] = winner ? 1 : 0;
                ws_f[1024 + tgt] = winner ? sqrtf(acc) : 0.0f;
            }
        }
    }
}

// ---------------------------------------------------------------------------
// K3: final combine (1 block, 256 threads = one thread per target)
// ---------------------------------------------------------------------------
__device__ __forceinline__ float block_sum(float v, float* red, int tid) {
    red[tid] = v;
    __syncthreads();
    for (int s = NT / 2; s > 0; s >>= 1) {
        if (tid < s) red[tid] += red[tid + s];
        __syncthreads();
    }
    float r = red[0];
    __syncthreads();
    return r;
}

__global__ __launch_bounds__(NT) void k3_final(
        const float* __restrict__ bbox_pred,
        const float* __restrict__ bbox_tgt,
        const float* __restrict__ ws_f,
        const int* __restrict__ ws_i,
        float* __restrict__ out) {
    const int tid = threadIdx.x;
    const int b = tid >> 3;
    __shared__ float s_red[NT];
    __shared__ int s_cnt[NT];

    bool valid; int gi, gj, best_a; float fx, fy, w, h;
    target_meta(bbox_tgt, tid, valid, gi, gj, fx, fy, w, h, best_a);
    int lin = ws_i[256 + tid];
    int winner = ws_i[512 + tid];
    float dist = ws_f[1024 + tid];

    float l0 = log1pf(fx), l1 = log1pf(fy), l2 = log1pf(w), l3 = log1pf(h);

    float c_nme = 0.0f, c_sl1 = 0.0f, c_cobj = 0.0f, c_csq = 0.0f;
    if (winner) {
        const float* bp = bbox_pred + (size_t)lin * 5;
        float conf = bp[4];
        c_cobj = (conf - 1.0f) * (conf - 1.0f);
        c_csq = conf * conf;
        float lb[4] = {l0, l1, l2, l3};
        for (int k = 0; k < 4; ++k) {
            float d = bp[k] - lb[k];
            float ad = fabsf(d);
            c_sl1 += (ad < 1.0f) ? 0.5f * d * d : (ad - 0.5f);
        }
        c_nme = dist / (sqrtf(l2 * l3) * 288.0f * 68.0f);
    }

    s_cnt[tid] = winner;
    __syncthreads();
    for (int s = NT / 2; s > 0; s >>= 1) {
        if (tid < s) s_cnt[tid] += s_cnt[tid + s];
        __syncthreads();
    }
    int cnt = s_cnt[0];
    __syncthreads();
    float nobj = fmaxf((float)cnt, 1.0f);
    float n_noobj = fmaxf((float)(NCELLS - cnt), 1.0f);

    float sum_nme  = block_sum(c_nme, s_red, tid);
    float sum_sl1  = block_sum(c_sl1, s_red, tid);
    float sum_cobj = block_sum(c_cobj, s_red, tid);
    float sum_csq  = block_sum(c_csq, s_red, tid);
    float s_total  = block_sum(tid < CONF_BLOCKS ? ws_f[tid] : 0.0f, s_red, tid);

    if (tid == 0) {
        out[0] = sum_nme / nobj;
        out[1] = 5.0f * sum_sl1 / (nobj * 4.0f);
        out[2] = 0.5f * (s_total - sum_csq) / n_noobj + sum_cobj / nobj;
    }

    // best_pred per target
    const float* cp = bbox_pred + (size_t)((b * Gc + gj) * Gc + gi) * Ac * 5;
    float x1g = l0 - l2 * 0.5f, x2g = l0 + l2 * 0.5f;
    float y1g = l1 - l3 * 0.5f, y2g = l1 + l3 * 0.5f;
    float ag = (x2g - x1g + 1.0f) * (y2g - y1g + 1.0f);
    int bp_idx = 0;
    float bp_iou = -1e30f;
    for (int a = 0; a < Ac; ++a) {
        float cx = cp[a * 5 + 0], cy = cp[a * 5 + 1];
        float pw = cp[a * 5 + 2], ph = cp[a * 5 + 3];
        float x1p = cx - pw * 0.5f, x2p = cx + pw * 0.5f;
        float y1p = cy - ph * 0.5f, y2p = cy + ph * 0.5f;
        float iw = fminf(x2g, x2p) - fmaxf(x1g, x1p) + 1.0f;
        float ih = fminf(y2g, y2p) - fmaxf(y1g, y1p) + 1.0f;
        float inter = iw * ih;
        float ap = (x2p - x1p + 1.0f) * (y2p - y1p + 1.0f);
        float iou = inter / (ag + ap - inter + 1e-16f);
        if (iou > bp_iou) { bp_iou = iou; bp_idx = a; }
    }
    float bx = cp[bp_idx * 5 + 0], by = cp[bp_idx * 5 + 1];
    float bw = cp[bp_idx * 5 + 2], bh = cp[bp_idx * 5 + 3];
    float bconf = cp[bp_idx * 5 + 4];
    float* op = out + 3 + (size_t)tid * 5;
    if (valid) {
        op[0] = bx - bw * 0.5f; op[1] = bx + bw * 0.5f;
        op[2] = by - bh * 0.5f; op[3] = by + bh * 0.5f; op[4] = bconf;
    } else {
        op[0] = 0.0f; op[1] = 0.0f; op[2] = 0.0f; op[3] = 0.0f; op[4] = 0.0f;
    }
}

extern "C" void kernel_launch(void* const* d_in, const int* in_sizes, int n_in,
                              void* d_out, int out_size, void* d_ws, size_t ws_size,
                              hipStream_t stream) {
    const float* bbox_pred = (const float*)d_in[0];
    const float* lm_pred   = (const float*)d_in[1];
    const float* bbox_tgt  = (const float*)d_in[2];
    const float* lm_tgt    = (const float*)d_in[3];
    float* out = (float*)d_out;
    float* ws_f = (float*)d_ws;
    int* ws_i = (int*)d_ws;

    k12_conf_lm<<<CONF_BLOCKS + 256, NT, 0, stream>>>(bbox_pred, lm_pred,
                                                      bbox_tgt, lm_tgt,
                                                      ws_f, ws_i);
    k3_final<<<1, NT, 0, stream>>>(bbox_pred, bbox_tgt, ws_f, ws_i, out);
}